// Round 1
// baseline (3837.258 us; speedup 1.0000x reference)
//
#include <hip/hip_runtime.h>
#include <math.h>

#define BB 4
#define NN 1024
#define EE 768
#define HH 12
#define DD 64
#define MLPH 1536
#define RR (BB*NN)

constexpr float EPS = 1e-6f;

__device__ __forceinline__ float gelu_exact(float x){
  return 0.5f * x * (1.0f + erff(x * 0.70710678118654752440f));
}

// ---------------- complex layernorm ----------------
// mode 0: inI interleaved [R][E][2];  mode 1: planar inR/inIm [R][E]
__global__ __launch_bounds__(256) void cln_kernel(
    const float* __restrict__ inI,
    const float* __restrict__ inR, const float* __restrict__ inIm,
    const float* __restrict__ gamma, const float* __restrict__ beta,
    float* __restrict__ outR, float* __restrict__ outI, int mode)
{
  int row = blockIdx.x;
  int t = threadIdx.x;
  __shared__ float sbuf[4];
  float vr[3], vi[3], mg[3];
  #pragma unroll
  for (int j=0;j<3;j++){
    int e = t + 256*j;
    float a, b;
    if (mode == 0){
      a = inI[(size_t)row*(2*EE) + 2*e];
      b = inI[(size_t)row*(2*EE) + 2*e + 1];
    } else {
      a = inR[(size_t)row*EE + e];
      b = inIm[(size_t)row*EE + e];
    }
    vr[j]=a; vi[j]=b;
    mg[j] = sqrtf(a*a + b*b + EPS);
  }
  int lane = t & 63, wv = t >> 6;
  float s = mg[0]+mg[1]+mg[2];
  #pragma unroll
  for (int o=32;o>0;o>>=1) s += __shfl_down(s, o, 64);
  if (lane==0) sbuf[wv] = s;
  __syncthreads();
  float mean = (sbuf[0]+sbuf[1]+sbuf[2]+sbuf[3]) * (1.0f/EE);
  __syncthreads();
  float v = 0.f;
  #pragma unroll
  for (int j=0;j<3;j++){ float d = mg[j]-mean; v += d*d; }
  #pragma unroll
  for (int o=32;o>0;o>>=1) v += __shfl_down(v, o, 64);
  if (lane==0) sbuf[wv] = v;
  __syncthreads();
  float var = (sbuf[0]+sbuf[1]+sbuf[2]+sbuf[3]) * (1.0f/EE);
  float inv = 1.0f / sqrtf(var + EPS);
  #pragma unroll
  for (int j=0;j<3;j++){
    int e = t + 256*j;
    float scale = ((mg[j]-mean) * inv) / (mg[j] + EPS);
    outR[(size_t)row*EE + e] = gamma[2*e]   * (vr[j]*scale) + beta[2*e];
    outI[(size_t)row*EE + e] = gamma[2*e+1] * (vi[j]*scale) + beta[2*e+1];
  }
}

// ---------------- complex GEMM ----------------
// out_r = xr@wr.T - xi@wi.T + br ; out_i = xr@wi.T + xi@wr.T + bi
// ACT: 0 none, 1 exact gelu (applied before residual per reference: gelu is its
//      own layer, residual only used on non-gelu layers here)
// RES_MODE: 0 none, 1 planar resr/resi [R][OUT], 2 interleaved resr [R][OUT][2]
// OUT_MODE: 0 planar outr/outi, 1 interleaved outr [R][OUT][2]
template<int ACT, int RES_MODE, int OUT_MODE>
__global__ __launch_bounds__(256) void cgemm_kernel(
    const float* __restrict__ xr, const float* __restrict__ xi,
    const float* __restrict__ wr, const float* __restrict__ wi,
    const float* __restrict__ br, const float* __restrict__ bi,
    const float* __restrict__ resr, const float* __restrict__ resi,
    float* __restrict__ outr, float* __restrict__ outi,
    int K, int OUT)
{
  __shared__ float Xr[64][17], Xi[64][17], Wr[64][17], Wi[64][17];
  int tid = threadIdx.x;
  int tx = tid & 15, ty = tid >> 4;
  int rowBase = blockIdx.y * 64, colBase = blockIdx.x * 64;
  float accR[4][4] = {}, accI[4][4] = {};
  int lk = tid & 15, lr4 = tid >> 4;
  for (int k0 = 0; k0 < K; k0 += 16){
    __syncthreads();
    #pragma unroll
    for (int p=0;p<4;p++){
      int rr = lr4 + p*16;
      Xr[rr][lk] = xr[(size_t)(rowBase+rr)*K + k0 + lk];
      Xi[rr][lk] = xi[(size_t)(rowBase+rr)*K + k0 + lk];
      Wr[rr][lk] = wr[(size_t)(colBase+rr)*K + k0 + lk];
      Wi[rr][lk] = wi[(size_t)(colBase+rr)*K + k0 + lk];
    }
    __syncthreads();
    #pragma unroll
    for (int kk=0;kk<16;kk++){
      float ar[4], ai[4], cr[4], ci[4];
      #pragma unroll
      for (int i=0;i<4;i++){ ar[i]=Xr[ty*4+i][kk]; ai[i]=Xi[ty*4+i][kk]; }
      #pragma unroll
      for (int j=0;j<4;j++){ cr[j]=Wr[tx*4+j][kk]; ci[j]=Wi[tx*4+j][kk]; }
      #pragma unroll
      for (int i=0;i<4;i++)
        #pragma unroll
        for (int j=0;j<4;j++){
          accR[i][j] = fmaf(ar[i], cr[j], fmaf(-ai[i], ci[j], accR[i][j]));
          accI[i][j] = fmaf(ar[i], ci[j], fmaf( ai[i], cr[j], accI[i][j]));
        }
    }
  }
  #pragma unroll
  for (int i=0;i<4;i++){
    int r = rowBase + ty*4 + i;
    #pragma unroll
    for (int j=0;j<4;j++){
      int c = colBase + tx*4 + j;
      float oR = accR[i][j] + br[c];
      float oI = accI[i][j] + bi[c];
      if (ACT == 1){ oR = gelu_exact(oR); oI = gelu_exact(oI); }
      if (RES_MODE == 1){
        oR += resr[(size_t)r*OUT + c];
        oI += resi[(size_t)r*OUT + c];
      } else if (RES_MODE == 2){
        oR += resr[(size_t)r*(2*OUT) + 2*c];
        oI += resr[(size_t)r*(2*OUT) + 2*c + 1];
      }
      if (OUT_MODE == 0){
        outr[(size_t)r*OUT + c] = oR;
        outi[(size_t)r*OUT + c] = oI;
      } else {
        outr[(size_t)r*(2*OUT) + 2*c]     = oR;
        outr[(size_t)r*(2*OUT) + 2*c + 1] = oI;
      }
    }
  }
}

// ---------------- complex flash attention ----------------
// scores: s = q . conj(k)-style per reference: s_r = qr.kr + qi.ki, s_i = qr.ki - qi.kr
// mag = sqrt(s_r^2+s_i^2+1e-8)/8 ; softmax over k ; out = w@v (r,i separately)
// block: 256 thr (4 waves), 16 q rows (4/wave), KV tiles of 32.
__global__ __launch_bounds__(256) void cattn_kernel(
    const float* __restrict__ qkvr, const float* __restrict__ qkvi,
    float* __restrict__ aor, float* __restrict__ aoi)
{
  int bh = blockIdx.y;
  int b = bh / HH, h = bh % HH;
  int qt = blockIdx.x;
  int tid = threadIdx.x;
  int lane = tid & 63, wv = tid >> 6;
  __shared__ float Kr[32][65], Ki[32][65], Vr[32][65], Vi[32][65];
  __shared__ float Qr[16][65], Qi[16][65];
  __shared__ float Wb[4][4][32];
  size_t rowQ0 = (size_t)b*NN + (size_t)qt*16;
  int qoff = h*DD, koff = EE + h*DD, voff = 2*EE + h*DD;

  #pragma unroll
  for (int p=0;p<4;p++){
    int rr = wv + p*4;
    Qr[rr][lane] = qkvr[(rowQ0+rr)*(3*EE) + qoff + lane];
    Qi[rr][lane] = qkvi[(rowQ0+rr)*(3*EE) + qoff + lane];
  }

  float m[4], l[4], aR[4], aI[4];
  #pragma unroll
  for (int j=0;j<4;j++){ m[j] = -INFINITY; l[j]=0.f; aR[j]=0.f; aI[j]=0.f; }

  int half = lane >> 5;      // which q-row of the pair this lane scores
  int kk = lane & 31;        // k index within tile

  for (int kt=0; kt<NN/32; kt++){
    __syncthreads();   // previous PV done before overwriting tiles
    size_t rowK0 = (size_t)b*NN + (size_t)kt*32;
    #pragma unroll
    for (int p=0;p<8;p++){
      int rr = wv + p*4;
      Kr[rr][lane] = qkvr[(rowK0+rr)*(3*EE) + koff + lane];
      Ki[rr][lane] = qkvi[(rowK0+rr)*(3*EE) + koff + lane];
      Vr[rr][lane] = qkvr[(rowK0+rr)*(3*EE) + voff + lane];
      Vi[rr][lane] = qkvi[(rowK0+rr)*(3*EE) + voff + lane];
    }
    __syncthreads();

    // score phase: 2 passes, each half-wave scores one of 2 rows over 32 k's
    #pragma unroll
    for (int jp=0;jp<2;jp++){
      int j0 = jp*2, j1 = jp*2 + 1;
      int qrow = wv*4 + j0 + half;
      float sr=0.f, si=0.f;
      #pragma unroll 16
      for (int d=0; d<DD; d++){
        float qr = Qr[qrow][d], qi = Qi[qrow][d];
        float kr = Kr[kk][d],  k_i = Ki[kk][d];
        sr = fmaf(qr, kr, fmaf(qi, k_i, sr));
        si = fmaf(qr, k_i, fmaf(-qi, kr, si));
      }
      float mg = sqrtf(fmaf(sr,sr, fmaf(si,si, 1e-8f))) * 0.125f;
      float mx = mg;
      #pragma unroll
      for (int o=16;o>0;o>>=1) mx = fmaxf(mx, __shfl_xor(mx, o, 32));
      float mold = (half==0) ? m[j0] : m[j1];
      float nm = fmaxf(mold, mx);
      float p  = expf(mg - nm);
      float alpha = expf(mold - nm);
      float ps = p;
      #pragma unroll
      for (int o=16;o>0;o>>=1) ps += __shfl_xor(ps, o, 32);
      // exchange per-row stats across the two halves so every lane has both rows
      float nm_o    = __shfl_xor(nm, 32, 64);
      float alpha_o = __shfl_xor(alpha, 32, 64);
      float ps_o    = __shfl_xor(ps, 32, 64);
      float nm0 = (half==0)? nm : nm_o,    nm1 = (half==0)? nm_o : nm;
      float al0 = (half==0)? alpha : alpha_o, al1 = (half==0)? alpha_o : alpha;
      float ps0 = (half==0)? ps : ps_o,    ps1 = (half==0)? ps_o : ps;
      m[j0]=nm0; m[j1]=nm1;
      l[j0]=l[j0]*al0 + ps0; l[j1]=l[j1]*al1 + ps1;
      aR[j0]*=al0; aI[j0]*=al0; aR[j1]*=al1; aI[j1]*=al1;
      Wb[wv][j0+half][kk] = p;
    }
    __syncthreads();  // Wb ready (uniform barrier across waves)

    // PV: lane owns dimension d=lane, accumulate 4 rows
    #pragma unroll 8
    for (int k2=0;k2<32;k2++){
      float vr = Vr[k2][lane], vi = Vi[k2][lane];
      #pragma unroll
      for (int j=0;j<4;j++){
        float p = Wb[wv][j][k2];
        aR[j] = fmaf(p, vr, aR[j]);
        aI[j] = fmaf(p, vi, aI[j]);
      }
    }
  }

  #pragma unroll
  for (int j=0;j<4;j++){
    size_t r = rowQ0 + wv*4 + j;
    float invl = 1.0f / l[j];
    aor[r*EE + qoff + lane] = aR[j]*invl;
    aoi[r*EE + qoff + lane] = aI[j]*invl;
  }
}

extern "C" void kernel_launch(void* const* d_in, const int* in_sizes, int n_in,
                              void* d_out, int out_size, void* d_ws, size_t ws_size,
                              hipStream_t stream) {
  const float* x       = (const float*)d_in[0];
  const float* g1      = (const float*)d_in[1];
  const float* b1      = (const float*)d_in[2];
  const float* g2      = (const float*)d_in[3];
  const float* b2      = (const float*)d_in[4];
  const float* qkv_wr  = (const float*)d_in[5];
  const float* qkv_wi  = (const float*)d_in[6];
  const float* qkv_br  = (const float*)d_in[7];
  const float* qkv_bi  = (const float*)d_in[8];
  const float* proj_wr = (const float*)d_in[9];
  const float* proj_wi = (const float*)d_in[10];
  const float* proj_br = (const float*)d_in[11];
  const float* proj_bi = (const float*)d_in[12];
  const float* m1_wr   = (const float*)d_in[13];
  const float* m1_wi   = (const float*)d_in[14];
  const float* m1_br   = (const float*)d_in[15];
  const float* m1_bi   = (const float*)d_in[16];
  const float* m2_wr   = (const float*)d_in[17];
  const float* m2_wi   = (const float*)d_in[18];
  const float* m2_br   = (const float*)d_in[19];
  const float* m2_bi   = (const float*)d_in[20];

  float* ws = (float*)d_ws;
  const size_t RE = (size_t)RR * EE;
  // region A (2*RE): xn1, then reused as attention output
  float* xn_r  = ws;            float* xn_i  = ws + RE;
  float* ao_r  = ws;            float* ao_i  = ws + RE;
  // region B (6*RE): qkv planar, then reused as xn2 (2*RE) + mlp hidden (4*RE)
  float* qkv_r = ws + 2*RE;     float* qkv_i = ws + 5*RE;
  float* xn2_r = ws + 2*RE;     float* xn2_i = ws + 3*RE;
  float* h_r   = ws + 4*RE;     float* h_i   = ws + 6*RE;
  // region C (2*RE): post-attention residual state x1
  float* x1_r  = ws + 8*RE;     float* x1_i  = ws + 9*RE;

  // 1. LN1 (interleaved in)
  cln_kernel<<<RR, 256, 0, stream>>>(x, nullptr, nullptr, g1, b1, xn_r, xn_i, 0);
  // 2. QKV clinear: [R,768c] -> [R,2304c]
  cgemm_kernel<0,0,0><<<dim3(36,64), 256, 0, stream>>>(
      xn_r, xn_i, qkv_wr, qkv_wi, qkv_br, qkv_bi,
      nullptr, nullptr, qkv_r, qkv_i, EE, 3*EE);
  // 3. attention -> ao [R][E] planar (e = h*64+d)
  cattn_kernel<<<dim3(64,48), 256, 0, stream>>>(qkv_r, qkv_i, ao_r, ao_i);
  // 4. proj clinear + residual(original x, interleaved) -> x1 planar
  cgemm_kernel<0,2,0><<<dim3(12,64), 256, 0, stream>>>(
      ao_r, ao_i, proj_wr, proj_wi, proj_br, proj_bi,
      x, nullptr, x1_r, x1_i, EE, EE);
  // 5. LN2 (planar in)
  cln_kernel<<<RR, 256, 0, stream>>>(nullptr, x1_r, x1_i, g2, b2, xn2_r, xn2_i, 1);
  // 6. MLP1 + exact gelu -> h [R][1536] planar
  cgemm_kernel<1,0,0><<<dim3(24,64), 256, 0, stream>>>(
      xn2_r, xn2_i, m1_wr, m1_wi, m1_br, m1_bi,
      nullptr, nullptr, h_r, h_i, EE, MLPH);
  // 7. MLP2 + residual(x1 planar) -> d_out interleaved
  cgemm_kernel<0,1,1><<<dim3(12,64), 256, 0, stream>>>(
      h_r, h_i, m2_wr, m2_wi, m2_br, m2_bi,
      x1_r, x1_i, (float*)d_out, nullptr, MLPH, EE);
}

// Round 2
// 1886.371 us; speedup vs baseline: 2.0342x; 2.0342x over previous
//
#include <hip/hip_runtime.h>
#include <math.h>

#define BB 4
#define NN 1024
#define EE 768
#define HH 12
#define DD 64
#define MLPH 1536
#define RR (BB*NN)

constexpr float EPS = 1e-6f;

typedef __bf16 bf16_t;
typedef bf16_t bf16x8 __attribute__((ext_vector_type(8)));
typedef bf16_t bf16x4 __attribute__((ext_vector_type(4)));
typedef float  f32x4  __attribute__((ext_vector_type(4)));
typedef unsigned short us8 __attribute__((ext_vector_type(8)));

__device__ __forceinline__ float gelu_exact(float x){
  return 0.5f * x * (1.0f + erff(x * 0.70710678118654752440f));
}

__device__ __forceinline__ bf16x8 negv(bf16x8 v){
  us8 u = __builtin_bit_cast(us8, v);
  u ^= (unsigned short)0x8000;
  return __builtin_bit_cast(bf16x8, u);
}

// split fp32x4 -> hi/lo bf16x4, store to LDS
__device__ __forceinline__ void cvtstore(bf16_t* hp, bf16_t* lp, f32x4 v){
  bf16x4 h, l;
  #pragma unroll
  for (int i=0;i<4;i++){
    float f = v[i];
    bf16_t hb = (bf16_t)f;
    h[i] = hb;
    l[i] = (bf16_t)(f - (float)hb);
  }
  *(bf16x4*)hp = h;
  *(bf16x4*)lp = l;
}

// ---------------- complex layernorm (unchanged) ----------------
__global__ __launch_bounds__(256) void cln_kernel(
    const float* __restrict__ inI,
    const float* __restrict__ inR, const float* __restrict__ inIm,
    const float* __restrict__ gamma, const float* __restrict__ beta,
    float* __restrict__ outR, float* __restrict__ outI, int mode)
{
  int row = blockIdx.x;
  int t = threadIdx.x;
  __shared__ float sbuf[4];
  float vr[3], vi[3], mg[3];
  #pragma unroll
  for (int j=0;j<3;j++){
    int e = t + 256*j;
    float a, b;
    if (mode == 0){
      a = inI[(size_t)row*(2*EE) + 2*e];
      b = inI[(size_t)row*(2*EE) + 2*e + 1];
    } else {
      a = inR[(size_t)row*EE + e];
      b = inIm[(size_t)row*EE + e];
    }
    vr[j]=a; vi[j]=b;
    mg[j] = sqrtf(a*a + b*b + EPS);
  }
  int lane = t & 63, wv = t >> 6;
  float s = mg[0]+mg[1]+mg[2];
  #pragma unroll
  for (int o=32;o>0;o>>=1) s += __shfl_down(s, o, 64);
  if (lane==0) sbuf[wv] = s;
  __syncthreads();
  float mean = (sbuf[0]+sbuf[1]+sbuf[2]+sbuf[3]) * (1.0f/EE);
  __syncthreads();
  float v = 0.f;
  #pragma unroll
  for (int j=0;j<3;j++){ float d = mg[j]-mean; v += d*d; }
  #pragma unroll
  for (int o=32;o>0;o>>=1) v += __shfl_down(v, o, 64);
  if (lane==0) sbuf[wv] = v;
  __syncthreads();
  float var = (sbuf[0]+sbuf[1]+sbuf[2]+sbuf[3]) * (1.0f/EE);
  float inv = 1.0f / sqrtf(var + EPS);
  #pragma unroll
  for (int j=0;j<3;j++){
    int e = t + 256*j;
    float scale = ((mg[j]-mean) * inv) / (mg[j] + EPS);
    outR[(size_t)row*EE + e] = gamma[2*e]   * (vr[j]*scale) + beta[2*e];
    outI[(size_t)row*EE + e] = gamma[2*e+1] * (vi[j]*scale) + beta[2*e+1];
  }
}

// ---------------- complex GEMM via bf16x3 MFMA ----------------
// out_r = xr@wr.T - xi@wi.T + br ; out_i = xr@wi.T + xi@wr.T + bi
// fp32 inputs split hi/lo bf16 during LDS staging; 3-term products per real GEMM.
// Block tile 128x64, BK=32, 4 waves (2x2) each 64x32 (4x2 frags of 16x16x32).
template<int ACT, int RES_MODE, int OUT_MODE>
__global__ __launch_bounds__(256) void cgemm_mfma(
    const float* __restrict__ xr, const float* __restrict__ xi,
    const float* __restrict__ wr, const float* __restrict__ wi,
    const float* __restrict__ br_, const float* __restrict__ bi_,
    const float* __restrict__ resr, const float* __restrict__ resi,
    float* __restrict__ outr, float* __restrict__ outi,
    int K, int OUT)
{
  __shared__ bf16_t Arh[128][40], Arl[128][40], Aih[128][40], Ail[128][40];
  __shared__ bf16_t Brh[64][40],  Brl[64][40],  Bih[64][40],  Bil[64][40];

  const int tid = threadIdx.x;
  const int rowBase = blockIdx.y * 128, colBase = blockIdx.x * 64;

  // staging coords: 8 threads per row-segment of 32 floats (128B)
  const int sr = tid >> 3;          // 0..31
  const int sc = (tid & 7) * 4;     // float col 0,4,...,28

  // compute coords
  const int wid = tid >> 6, lane = tid & 63;
  const int wr0 = (wid >> 1) * 64, wc0 = (wid & 1) * 32;
  const int fr = lane & 15, fq = lane >> 4;

  f32x4 accR[4][2], accI[4][2];
  #pragma unroll
  for (int mi=0;mi<4;mi++)
    #pragma unroll
    for (int ni=0;ni<2;ni++){ accR[mi][ni] = (f32x4)0.f; accI[mi][ni] = (f32x4)0.f; }

  f32x4 pAr[4], pAi[4], pBr[2], pBi[2];

  auto LOAD = [&](int k0){
    #pragma unroll
    for (int it=0; it<4; it++){
      const size_t ro = (size_t)(rowBase + sr + it*32)*K + k0 + sc;
      pAr[it] = *(const f32x4*)(xr + ro);
      pAi[it] = *(const f32x4*)(xi + ro);
    }
    #pragma unroll
    for (int it=0; it<2; it++){
      const size_t ro = (size_t)(colBase + sr + it*32)*K + k0 + sc;
      pBr[it] = *(const f32x4*)(wr + ro);
      pBi[it] = *(const f32x4*)(wi + ro);
    }
  };

  LOAD(0);

  for (int k0 = 0; k0 < K; k0 += 32){
    __syncthreads();   // previous compute done with LDS
    #pragma unroll
    for (int it=0; it<4; it++){
      int r = sr + it*32;
      cvtstore(&Arh[r][sc], &Arl[r][sc], pAr[it]);
      cvtstore(&Aih[r][sc], &Ail[r][sc], pAi[it]);
    }
    #pragma unroll
    for (int it=0; it<2; it++){
      int r = sr + it*32;
      cvtstore(&Brh[r][sc], &Brl[r][sc], pBr[it]);
      cvtstore(&Bih[r][sc], &Bil[r][sc], pBi[it]);
    }
    __syncthreads();   // LDS tile ready
    if (k0 + 32 < K) LOAD(k0 + 32);

    bf16x8 brh[2], brl[2], bih[2], bil[2];
    #pragma unroll
    for (int ni=0; ni<2; ni++){
      int c = wc0 + ni*16 + fr;
      brh[ni] = *(const bf16x8*)&Brh[c][fq*8];
      brl[ni] = *(const bf16x8*)&Brl[c][fq*8];
      bih[ni] = *(const bf16x8*)&Bih[c][fq*8];
      bil[ni] = *(const bf16x8*)&Bil[c][fq*8];
    }
    #pragma unroll
    for (int mi=0; mi<4; mi++){
      int r = wr0 + mi*16 + fr;
      bf16x8 arh = *(const bf16x8*)&Arh[r][fq*8];
      bf16x8 arl = *(const bf16x8*)&Arl[r][fq*8];
      bf16x8 aih = *(const bf16x8*)&Aih[r][fq*8];
      bf16x8 ail = *(const bf16x8*)&Ail[r][fq*8];
      bf16x8 nih = negv(aih), nil_ = negv(ail);
      #pragma unroll
      for (int ni=0; ni<2; ni++){
        f32x4 cR = accR[mi][ni], cI = accI[mi][ni];
        cR = __builtin_amdgcn_mfma_f32_16x16x32_bf16(arh, brh[ni], cR, 0,0,0);
        cR = __builtin_amdgcn_mfma_f32_16x16x32_bf16(arh, brl[ni], cR, 0,0,0);
        cR = __builtin_amdgcn_mfma_f32_16x16x32_bf16(arl, brh[ni], cR, 0,0,0);
        cR = __builtin_amdgcn_mfma_f32_16x16x32_bf16(nih, bih[ni], cR, 0,0,0);
        cR = __builtin_amdgcn_mfma_f32_16x16x32_bf16(nih, bil[ni], cR, 0,0,0);
        cR = __builtin_amdgcn_mfma_f32_16x16x32_bf16(nil_, bih[ni], cR, 0,0,0);
        cI = __builtin_amdgcn_mfma_f32_16x16x32_bf16(arh, bih[ni], cI, 0,0,0);
        cI = __builtin_amdgcn_mfma_f32_16x16x32_bf16(arh, bil[ni], cI, 0,0,0);
        cI = __builtin_amdgcn_mfma_f32_16x16x32_bf16(arl, bih[ni], cI, 0,0,0);
        cI = __builtin_amdgcn_mfma_f32_16x16x32_bf16(aih, brh[ni], cI, 0,0,0);
        cI = __builtin_amdgcn_mfma_f32_16x16x32_bf16(aih, brl[ni], cI, 0,0,0);
        cI = __builtin_amdgcn_mfma_f32_16x16x32_bf16(ail, brh[ni], cI, 0,0,0);
        accR[mi][ni] = cR; accI[mi][ni] = cI;
      }
    }
  }

  // epilogue: C/D layout col=lane&15 (=fr), row=(lane>>4)*4+j (=fq*4+j)
  #pragma unroll
  for (int mi=0; mi<4; mi++){
    #pragma unroll
    for (int ni=0; ni<2; ni++){
      #pragma unroll
      for (int j=0; j<4; j++){
        int r = rowBase + wr0 + mi*16 + fq*4 + j;
        int c = colBase + wc0 + ni*16 + fr;
        float oR = accR[mi][ni][j] + br_[c];
        float oI = accI[mi][ni][j] + bi_[c];
        if (ACT == 1){ oR = gelu_exact(oR); oI = gelu_exact(oI); }
        if (RES_MODE == 1){
          oR += resr[(size_t)r*OUT + c];
          oI += resi[(size_t)r*OUT + c];
        } else if (RES_MODE == 2){
          oR += resr[(size_t)r*(2*OUT) + 2*c];
          oI += resr[(size_t)r*(2*OUT) + 2*c + 1];
        }
        if (OUT_MODE == 0){
          outr[(size_t)r*OUT + c] = oR;
          outi[(size_t)r*OUT + c] = oI;
        } else {
          outr[(size_t)r*(2*OUT) + 2*c]     = oR;
          outr[(size_t)r*(2*OUT) + 2*c + 1] = oI;
        }
      }
    }
  }
}

// ---------------- complex flash attention (unchanged) ----------------
__global__ __launch_bounds__(256) void cattn_kernel(
    const float* __restrict__ qkvr, const float* __restrict__ qkvi,
    float* __restrict__ aor, float* __restrict__ aoi)
{
  int bh = blockIdx.y;
  int b = bh / HH, h = bh % HH;
  int qt = blockIdx.x;
  int tid = threadIdx.x;
  int lane = tid & 63, wv = tid >> 6;
  __shared__ float Kr[32][65], Ki[32][65], Vr[32][65], Vi[32][65];
  __shared__ float Qr[16][65], Qi[16][65];
  __shared__ float Wb[4][4][32];
  size_t rowQ0 = (size_t)b*NN + (size_t)qt*16;
  int qoff = h*DD, koff = EE + h*DD, voff = 2*EE + h*DD;

  #pragma unroll
  for (int p=0;p<4;p++){
    int rr = wv + p*4;
    Qr[rr][lane] = qkvr[(rowQ0+rr)*(3*EE) + qoff + lane];
    Qi[rr][lane] = qkvi[(rowQ0+rr)*(3*EE) + qoff + lane];
  }

  float m[4], l[4], aR[4], aI[4];
  #pragma unroll
  for (int j=0;j<4;j++){ m[j] = -INFINITY; l[j]=0.f; aR[j]=0.f; aI[j]=0.f; }

  int half = lane >> 5;
  int kk = lane & 31;

  for (int kt=0; kt<NN/32; kt++){
    __syncthreads();
    size_t rowK0 = (size_t)b*NN + (size_t)kt*32;
    #pragma unroll
    for (int p=0;p<8;p++){
      int rr = wv + p*4;
      Kr[rr][lane] = qkvr[(rowK0+rr)*(3*EE) + koff + lane];
      Ki[rr][lane] = qkvi[(rowK0+rr)*(3*EE) + koff + lane];
      Vr[rr][lane] = qkvr[(rowK0+rr)*(3*EE) + voff + lane];
      Vi[rr][lane] = qkvi[(rowK0+rr)*(3*EE) + voff + lane];
    }
    __syncthreads();

    #pragma unroll
    for (int jp=0;jp<2;jp++){
      int j0 = jp*2, j1 = jp*2 + 1;
      int qrow = wv*4 + j0 + half;
      float sr=0.f, si=0.f;
      #pragma unroll 16
      for (int d=0; d<DD; d++){
        float qr = Qr[qrow][d], qi = Qi[qrow][d];
        float kr = Kr[kk][d],  k_i = Ki[kk][d];
        sr = fmaf(qr, kr, fmaf(qi, k_i, sr));
        si = fmaf(qr, k_i, fmaf(-qi, kr, si));
      }
      float mg = sqrtf(fmaf(sr,sr, fmaf(si,si, 1e-8f))) * 0.125f;
      float mx = mg;
      #pragma unroll
      for (int o=16;o>0;o>>=1) mx = fmaxf(mx, __shfl_xor(mx, o, 32));
      float mold = (half==0) ? m[j0] : m[j1];
      float nm = fmaxf(mold, mx);
      float p  = expf(mg - nm);
      float alpha = expf(mold - nm);
      float ps = p;
      #pragma unroll
      for (int o=16;o>0;o>>=1) ps += __shfl_xor(ps, o, 32);
      float nm_o    = __shfl_xor(nm, 32, 64);
      float alpha_o = __shfl_xor(alpha, 32, 64);
      float ps_o    = __shfl_xor(ps, 32, 64);
      float nm0 = (half==0)? nm : nm_o,    nm1 = (half==0)? nm_o : nm;
      float al0 = (half==0)? alpha : alpha_o, al1 = (half==0)? alpha_o : alpha;
      float ps0 = (half==0)? ps : ps_o,    ps1 = (half==0)? ps_o : ps;
      m[j0]=nm0; m[j1]=nm1;
      l[j0]=l[j0]*al0 + ps0; l[j1]=l[j1]*al1 + ps1;
      aR[j0]*=al0; aI[j0]*=al0; aR[j1]*=al1; aI[j1]*=al1;
      Wb[wv][j0+half][kk] = p;
    }
    __syncthreads();

    #pragma unroll 8
    for (int k2=0;k2<32;k2++){
      float vr = Vr[k2][lane], vi = Vi[k2][lane];
      #pragma unroll
      for (int j=0;j<4;j++){
        float p = Wb[wv][j][k2];
        aR[j] = fmaf(p, vr, aR[j]);
        aI[j] = fmaf(p, vi, aI[j]);
      }
    }
  }

  #pragma unroll
  for (int j=0;j<4;j++){
    size_t r = rowQ0 + wv*4 + j;
    float invl = 1.0f / l[j];
    aor[r*EE + qoff + lane] = aR[j]*invl;
    aoi[r*EE + qoff + lane] = aI[j]*invl;
  }
}

extern "C" void kernel_launch(void* const* d_in, const int* in_sizes, int n_in,
                              void* d_out, int out_size, void* d_ws, size_t ws_size,
                              hipStream_t stream) {
  const float* x       = (const float*)d_in[0];
  const float* g1      = (const float*)d_in[1];
  const float* b1      = (const float*)d_in[2];
  const float* g2      = (const float*)d_in[3];
  const float* b2      = (const float*)d_in[4];
  const float* qkv_wr  = (const float*)d_in[5];
  const float* qkv_wi  = (const float*)d_in[6];
  const float* qkv_br  = (const float*)d_in[7];
  const float* qkv_bi  = (const float*)d_in[8];
  const float* proj_wr = (const float*)d_in[9];
  const float* proj_wi = (const float*)d_in[10];
  const float* proj_br = (const float*)d_in[11];
  const float* proj_bi = (const float*)d_in[12];
  const float* m1_wr   = (const float*)d_in[13];
  const float* m1_wi   = (const float*)d_in[14];
  const float* m1_br   = (const float*)d_in[15];
  const float* m1_bi   = (const float*)d_in[16];
  const float* m2_wr   = (const float*)d_in[17];
  const float* m2_wi   = (const float*)d_in[18];
  const float* m2_br   = (const float*)d_in[19];
  const float* m2_bi   = (const float*)d_in[20];

  float* ws = (float*)d_ws;
  const size_t RE = (size_t)RR * EE;
  float* xn_r  = ws;            float* xn_i  = ws + RE;
  float* ao_r  = ws;            float* ao_i  = ws + RE;
  float* qkv_r = ws + 2*RE;     float* qkv_i = ws + 5*RE;
  float* xn2_r = ws + 2*RE;     float* xn2_i = ws + 3*RE;
  float* h_r   = ws + 4*RE;     float* h_i   = ws + 6*RE;
  float* x1_r  = ws + 8*RE;     float* x1_i  = ws + 9*RE;

  // 1. LN1 (interleaved in)
  cln_kernel<<<RR, 256, 0, stream>>>(x, nullptr, nullptr, g1, b1, xn_r, xn_i, 0);
  // 2. QKV clinear: [R,768c] -> [R,2304c]
  cgemm_mfma<0,0,0><<<dim3(36,32), 256, 0, stream>>>(
      xn_r, xn_i, qkv_wr, qkv_wi, qkv_br, qkv_bi,
      nullptr, nullptr, qkv_r, qkv_i, EE, 3*EE);
  // 3. attention -> ao [R][E] planar
  cattn_kernel<<<dim3(64,48), 256, 0, stream>>>(qkv_r, qkv_i, ao_r, ao_i);
  // 4. proj clinear + residual(original x, interleaved) -> x1 planar
  cgemm_mfma<0,2,0><<<dim3(12,32), 256, 0, stream>>>(
      ao_r, ao_i, proj_wr, proj_wi, proj_br, proj_bi,
      x, nullptr, x1_r, x1_i, EE, EE);
  // 5. LN2 (planar in)
  cln_kernel<<<RR, 256, 0, stream>>>(nullptr, x1_r, x1_i, g2, b2, xn2_r, xn2_i, 1);
  // 6. MLP1 + exact gelu -> h [R][1536] planar
  cgemm_mfma<1,0,0><<<dim3(24,32), 256, 0, stream>>>(
      xn2_r, xn2_i, m1_wr, m1_wi, m1_br, m1_bi,
      nullptr, nullptr, h_r, h_i, EE, MLPH);
  // 7. MLP2 + residual(x1 planar) -> d_out interleaved
  cgemm_mfma<0,1,1><<<dim3(12,32), 256, 0, stream>>>(
      h_r, h_i, m2_wr, m2_wi, m2_br, m2_bi,
      x1_r, x1_i, (float*)d_out, nullptr, MLPH, EE);
}

// Round 4
// 903.310 us; speedup vs baseline: 4.2480x; 2.0883x over previous
//
#include <hip/hip_runtime.h>
#include <math.h>

#define BB 4
#define NN 1024
#define EE 768
#define HH 12
#define DD 64
#define MLPH 1536
#define RR (BB*NN)
#define SZH ((size_t)48*1024*64)   // elements per split attention array

constexpr float EPS = 1e-6f;

typedef __bf16 bf16_t;
typedef bf16_t bf16x8 __attribute__((ext_vector_type(8)));
typedef bf16_t bf16x4 __attribute__((ext_vector_type(4)));
typedef float  f32x4  __attribute__((ext_vector_type(4)));
typedef unsigned short us8 __attribute__((ext_vector_type(8)));

__device__ __forceinline__ float gelu_exact(float x){
  return 0.5f * x * (1.0f + erff(x * 0.70710678118654752440f));
}

__device__ __forceinline__ bf16x8 negv(bf16x8 v){
  us8 u = __builtin_bit_cast(us8, v);
  u ^= (unsigned short)0x8000;
  return __builtin_bit_cast(bf16x8, u);
}

// split fp32x4 -> hi/lo bf16x4, store to LDS
__device__ __forceinline__ void cvtstore(bf16_t* hp, bf16_t* lp, f32x4 v){
  bf16x4 h, l;
  #pragma unroll
  for (int i=0;i<4;i++){
    float f = v[i];
    bf16_t hb = (bf16_t)f;
    h[i] = hb;
    l[i] = (bf16_t)(f - (float)hb);
  }
  *(bf16x4*)hp = h;
  *(bf16x4*)lp = l;
}

// ---------------- complex layernorm (unchanged) ----------------
__global__ __launch_bounds__(256) void cln_kernel(
    const float* __restrict__ inI,
    const float* __restrict__ inR, const float* __restrict__ inIm,
    const float* __restrict__ gamma, const float* __restrict__ beta,
    float* __restrict__ outR, float* __restrict__ outI, int mode)
{
  int row = blockIdx.x;
  int t = threadIdx.x;
  __shared__ float sbuf[4];
  float vr[3], vi[3], mg[3];
  #pragma unroll
  for (int j=0;j<3;j++){
    int e = t + 256*j;
    float a, b;
    if (mode == 0){
      a = inI[(size_t)row*(2*EE) + 2*e];
      b = inI[(size_t)row*(2*EE) + 2*e + 1];
    } else {
      a = inR[(size_t)row*EE + e];
      b = inIm[(size_t)row*EE + e];
    }
    vr[j]=a; vi[j]=b;
    mg[j] = sqrtf(a*a + b*b + EPS);
  }
  int lane = t & 63, wv = t >> 6;
  float s = mg[0]+mg[1]+mg[2];
  #pragma unroll
  for (int o=32;o>0;o>>=1) s += __shfl_down(s, o, 64);
  if (lane==0) sbuf[wv] = s;
  __syncthreads();
  float mean = (sbuf[0]+sbuf[1]+sbuf[2]+sbuf[3]) * (1.0f/EE);
  __syncthreads();
  float v = 0.f;
  #pragma unroll
  for (int j=0;j<3;j++){ float d = mg[j]-mean; v += d*d; }
  #pragma unroll
  for (int o=32;o>0;o>>=1) v += __shfl_down(v, o, 64);
  if (lane==0) sbuf[wv] = v;
  __syncthreads();
  float var = (sbuf[0]+sbuf[1]+sbuf[2]+sbuf[3]) * (1.0f/EE);
  float inv = 1.0f / sqrtf(var + EPS);
  #pragma unroll
  for (int j=0;j<3;j++){
    int e = t + 256*j;
    float scale = ((mg[j]-mean) * inv) / (mg[j] + EPS);
    outR[(size_t)row*EE + e] = gamma[2*e]   * (vr[j]*scale) + beta[2*e];
    outI[(size_t)row*EE + e] = gamma[2*e+1] * (vi[j]*scale) + beta[2*e+1];
  }
}

// ---------------- complex GEMM via bf16x3 MFMA ----------------
// OUT_MODE: 0 planar fp32, 1 interleaved fp32, 2 QKV split bf16 arrays
template<int ACT, int RES_MODE, int OUT_MODE>
__global__ __launch_bounds__(256) void cgemm_mfma(
    const float* __restrict__ xr, const float* __restrict__ xi,
    const float* __restrict__ wr, const float* __restrict__ wi,
    const float* __restrict__ br_, const float* __restrict__ bi_,
    const float* __restrict__ resr, const float* __restrict__ resi,
    float* __restrict__ outr, float* __restrict__ outi,
    bf16_t* __restrict__ qsplit,
    int K, int OUT)
{
  __shared__ bf16_t Arh[128][40], Arl[128][40], Aih[128][40], Ail[128][40];
  __shared__ bf16_t Brh[64][40],  Brl[64][40],  Bih[64][40],  Bil[64][40];

  const int tid = threadIdx.x;
  const int rowBase = blockIdx.y * 128, colBase = blockIdx.x * 64;

  const int sr = tid >> 3;
  const int sc = (tid & 7) * 4;

  const int wid = tid >> 6, lane = tid & 63;
  const int wr0 = (wid >> 1) * 64, wc0 = (wid & 1) * 32;
  const int fr = lane & 15, fq = lane >> 4;

  f32x4 accR[4][2], accI[4][2];
  #pragma unroll
  for (int mi=0;mi<4;mi++)
    #pragma unroll
    for (int ni=0;ni<2;ni++){ accR[mi][ni] = (f32x4)0.f; accI[mi][ni] = (f32x4)0.f; }

  f32x4 pAr[4], pAi[4], pBr[2], pBi[2];

  auto LOAD = [&](int k0){
    #pragma unroll
    for (int it=0; it<4; it++){
      const size_t ro = (size_t)(rowBase + sr + it*32)*K + k0 + sc;
      pAr[it] = *(const f32x4*)(xr + ro);
      pAi[it] = *(const f32x4*)(xi + ro);
    }
    #pragma unroll
    for (int it=0; it<2; it++){
      const size_t ro = (size_t)(colBase + sr + it*32)*K + k0 + sc;
      pBr[it] = *(const f32x4*)(wr + ro);
      pBi[it] = *(const f32x4*)(wi + ro);
    }
  };

  LOAD(0);

  for (int k0 = 0; k0 < K; k0 += 32){
    __syncthreads();
    #pragma unroll
    for (int it=0; it<4; it++){
      int r = sr + it*32;
      cvtstore(&Arh[r][sc], &Arl[r][sc], pAr[it]);
      cvtstore(&Aih[r][sc], &Ail[r][sc], pAi[it]);
    }
    #pragma unroll
    for (int it=0; it<2; it++){
      int r = sr + it*32;
      cvtstore(&Brh[r][sc], &Brl[r][sc], pBr[it]);
      cvtstore(&Bih[r][sc], &Bil[r][sc], pBi[it]);
    }
    __syncthreads();
    if (k0 + 32 < K) LOAD(k0 + 32);

    bf16x8 brh[2], brl[2], bih[2], bil[2];
    #pragma unroll
    for (int ni=0; ni<2; ni++){
      int c = wc0 + ni*16 + fr;
      brh[ni] = *(const bf16x8*)&Brh[c][fq*8];
      brl[ni] = *(const bf16x8*)&Brl[c][fq*8];
      bih[ni] = *(const bf16x8*)&Bih[c][fq*8];
      bil[ni] = *(const bf16x8*)&Bil[c][fq*8];
    }
    #pragma unroll
    for (int mi=0; mi<4; mi++){
      int r = wr0 + mi*16 + fr;
      bf16x8 arh = *(const bf16x8*)&Arh[r][fq*8];
      bf16x8 arl = *(const bf16x8*)&Arl[r][fq*8];
      bf16x8 aih = *(const bf16x8*)&Aih[r][fq*8];
      bf16x8 ail = *(const bf16x8*)&Ail[r][fq*8];
      bf16x8 nih = negv(aih), nil_ = negv(ail);
      #pragma unroll
      for (int ni=0; ni<2; ni++){
        f32x4 cR = accR[mi][ni], cI = accI[mi][ni];
        cR = __builtin_amdgcn_mfma_f32_16x16x32_bf16(arh, brh[ni], cR, 0,0,0);
        cR = __builtin_amdgcn_mfma_f32_16x16x32_bf16(arh, brl[ni], cR, 0,0,0);
        cR = __builtin_amdgcn_mfma_f32_16x16x32_bf16(arl, brh[ni], cR, 0,0,0);
        cR = __builtin_amdgcn_mfma_f32_16x16x32_bf16(nih, bih[ni], cR, 0,0,0);
        cR = __builtin_amdgcn_mfma_f32_16x16x32_bf16(nih, bil[ni], cR, 0,0,0);
        cR = __builtin_amdgcn_mfma_f32_16x16x32_bf16(nil_, bih[ni], cR, 0,0,0);
        cI = __builtin_amdgcn_mfma_f32_16x16x32_bf16(arh, bih[ni], cI, 0,0,0);
        cI = __builtin_amdgcn_mfma_f32_16x16x32_bf16(arh, bil[ni], cI, 0,0,0);
        cI = __builtin_amdgcn_mfma_f32_16x16x32_bf16(arl, bih[ni], cI, 0,0,0);
        cI = __builtin_amdgcn_mfma_f32_16x16x32_bf16(aih, brh[ni], cI, 0,0,0);
        cI = __builtin_amdgcn_mfma_f32_16x16x32_bf16(aih, brl[ni], cI, 0,0,0);
        cI = __builtin_amdgcn_mfma_f32_16x16x32_bf16(ail, brh[ni], cI, 0,0,0);
        accR[mi][ni] = cR; accI[mi][ni] = cI;
      }
    }
  }

  #pragma unroll
  for (int mi=0; mi<4; mi++){
    #pragma unroll
    for (int ni=0; ni<2; ni++){
      #pragma unroll
      for (int j=0; j<4; j++){
        int r = rowBase + wr0 + mi*16 + fq*4 + j;
        int c = colBase + wc0 + ni*16 + fr;
        float oR = accR[mi][ni][j] + br_[c];
        float oI = accI[mi][ni][j] + bi_[c];
        if (ACT == 1){ oR = gelu_exact(oR); oI = gelu_exact(oI); }
        if (RES_MODE == 1){
          oR += resr[(size_t)r*OUT + c];
          oI += resi[(size_t)r*OUT + c];
        } else if (RES_MODE == 2){
          oR += resr[(size_t)r*(2*OUT) + 2*c];
          oI += resr[(size_t)r*(2*OUT) + 2*c + 1];
        }
        if (OUT_MODE == 0){
          outr[(size_t)r*OUT + c] = oR;
          outi[(size_t)r*OUT + c] = oI;
        } else if (OUT_MODE == 1){
          outr[(size_t)r*(2*OUT) + 2*c]     = oR;
          outr[(size_t)r*(2*OUT) + 2*c + 1] = oI;
        } else {
          // QKV split bf16: Q,K -> [bh][n][64]; V -> [bh][64][n]
          int part = c / EE; int win = c - part*EE;
          int hh = win >> 6, dd = win & 63;
          int bq = r >> 10, nq = r & 1023;
          int bhh = bq*HH + hh;
          size_t idx = (part < 2) ? (((size_t)bhh*NN + nq)*DD + dd)
                                  : (((size_t)bhh*DD + dd)*NN + nq);
          bf16_t* bas = qsplit + (size_t)part*4*SZH;
          bf16_t hR = (bf16_t)oR; bf16_t lR2 = (bf16_t)(oR - (float)hR);
          bf16_t hI = (bf16_t)oI; bf16_t lI2 = (bf16_t)(oI - (float)hI);
          bas[idx]         = hR;
          bas[SZH + idx]   = lR2;
          bas[2*SZH + idx] = hI;
          bas[3*SZH + idx] = lI2;
        }
      }
    }
  }
}

// ---------------- complex flash attention via MFMA ----------------
// scores s_r = qr.kr + qi.ki, s_i = qr.ki - qi.kr (bf16x3); mag = sqrt(..+1e-8)/8;
// online softmax; PV with bf16 P (h only) x bf16 V (h+l).
// Block: 4 waves, 64 q rows (16/wave), k-tiles of 32, one (b,h) per blockIdx.y.
__global__ __launch_bounds__(256) void cattn_mfma(
    const bf16_t* __restrict__ qs,
    float* __restrict__ aor, float* __restrict__ aoi)
{
  __shared__ bf16_t Krh[32][72], Krl[32][72], Kih[32][72], Kil[32][72];
  __shared__ bf16_t Vrh[64][40], Vrl[64][40], Vih[64][40], Vil[64][40];
  __shared__ bf16_t Pl[4][16][40];

  const int tid = threadIdx.x;
  const int lane = tid & 63, wid = tid >> 6;
  const int fr = lane & 15, fq = lane >> 4;
  const int qt = blockIdx.x, bh = blockIdx.y;
  const int b = bh / HH, h = bh - b*HH;

  const bf16_t* Qb = qs;
  const bf16_t* Kb = qs + 4*SZH;
  const bf16_t* Vb = qs + 8*SZH;

  // Q A-fragments: row(lane&15)=q, k-dim chunk at fq*8
  const int qrow = qt*64 + wid*16 + fr;
  bf16x8 q_rh[2], q_rl[2], q_ih[2], q_il[2], nq_ih[2], nq_il[2];
  #pragma unroll
  for (int c=0;c<2;c++){
    size_t o = ((size_t)bh*NN + qrow)*DD + c*32 + fq*8;
    q_rh[c] = *(const bf16x8*)(Qb + 0*SZH + o);
    q_rl[c] = *(const bf16x8*)(Qb + 1*SZH + o);
    q_ih[c] = *(const bf16x8*)(Qb + 2*SZH + o);
    q_il[c] = *(const bf16x8*)(Qb + 3*SZH + o);
    nq_ih[c] = negv(q_ih[c]);
    nq_il[c] = negv(q_il[c]);
  }

  f32x4 accOr[4], accOi[4];
  #pragma unroll
  for (int df=0;df<4;df++){ accOr[df] = (f32x4)0.f; accOi[df] = (f32x4)0.f; }
  float m[4] = {0.f,0.f,0.f,0.f}, l[4] = {0.f,0.f,0.f,0.f};

  const int skr = tid >> 3, skc = (tid & 7) * 8;   // K stage: 32 x 64
  const int svr = tid >> 2, svc = (tid & 3) * 8;   // V stage: 64 x 32

  for (int kt = 0; kt < NN/32; kt++){
    __syncthreads();
    {
      size_t kb = ((size_t)bh*NN + kt*32 + skr)*DD + skc;
      *(bf16x8*)&Krh[skr][skc] = *(const bf16x8*)(Kb + 0*SZH + kb);
      *(bf16x8*)&Krl[skr][skc] = *(const bf16x8*)(Kb + 1*SZH + kb);
      *(bf16x8*)&Kih[skr][skc] = *(const bf16x8*)(Kb + 2*SZH + kb);
      *(bf16x8*)&Kil[skr][skc] = *(const bf16x8*)(Kb + 3*SZH + kb);
      size_t vb = ((size_t)bh*DD + svr)*NN + kt*32 + svc;
      *(bf16x8*)&Vrh[svr][svc] = *(const bf16x8*)(Vb + 0*SZH + vb);
      *(bf16x8*)&Vrl[svr][svc] = *(const bf16x8*)(Vb + 1*SZH + vb);
      *(bf16x8*)&Vih[svr][svc] = *(const bf16x8*)(Vb + 2*SZH + vb);
      *(bf16x8*)&Vil[svr][svc] = *(const bf16x8*)(Vb + 3*SZH + vb);
    }
    __syncthreads();

    // QK^T: 2 k-frags x (12 MFMA s_r + 12 MFMA s_i)
    f32x4 sr[2], si[2];
    #pragma unroll
    for (int f=0; f<2; f++){
      f32x4 r = (f32x4)0.f, im = (f32x4)0.f;
      #pragma unroll
      for (int c=0; c<2; c++){
        const int kr_ = f*16 + fr, co = c*32 + fq*8;
        bf16x8 krh = *(const bf16x8*)&Krh[kr_][co];
        bf16x8 krl = *(const bf16x8*)&Krl[kr_][co];
        bf16x8 kih = *(const bf16x8*)&Kih[kr_][co];
        bf16x8 kil = *(const bf16x8*)&Kil[kr_][co];
        r = __builtin_amdgcn_mfma_f32_16x16x32_bf16(q_rh[c], krh, r, 0,0,0);
        r = __builtin_amdgcn_mfma_f32_16x16x32_bf16(q_rh[c], krl, r, 0,0,0);
        r = __builtin_amdgcn_mfma_f32_16x16x32_bf16(q_rl[c], krh, r, 0,0,0);
        r = __builtin_amdgcn_mfma_f32_16x16x32_bf16(q_ih[c], kih, r, 0,0,0);
        r = __builtin_amdgcn_mfma_f32_16x16x32_bf16(q_ih[c], kil, r, 0,0,0);
        r = __builtin_amdgcn_mfma_f32_16x16x32_bf16(q_il[c], kih, r, 0,0,0);
        im = __builtin_amdgcn_mfma_f32_16x16x32_bf16(q_rh[c], kih, im, 0,0,0);
        im = __builtin_amdgcn_mfma_f32_16x16x32_bf16(q_rh[c], kil, im, 0,0,0);
        im = __builtin_amdgcn_mfma_f32_16x16x32_bf16(q_rl[c], kih, im, 0,0,0);
        im = __builtin_amdgcn_mfma_f32_16x16x32_bf16(nq_ih[c], krh, im, 0,0,0);
        im = __builtin_amdgcn_mfma_f32_16x16x32_bf16(nq_ih[c], krl, im, 0,0,0);
        im = __builtin_amdgcn_mfma_f32_16x16x32_bf16(nq_il[c], krh, im, 0,0,0);
      }
      sr[f] = r; si[f] = im;
    }

    // softmax (online). score frag: col=k=f*16+fr, row=q=fq*4+j
    float mg[2][4];
    #pragma unroll
    for (int f=0; f<2; f++)
      #pragma unroll
      for (int j=0; j<4; j++){
        float a = sr[f][j], c2 = si[f][j];
        mg[f][j] = sqrtf(fmaf(a,a, fmaf(c2,c2, 1e-8f))) * 0.125f;
      }
    float al[4];
    #pragma unroll
    for (int j=0; j<4; j++){
      float mx = fmaxf(mg[0][j], mg[1][j]);
      mx = fmaxf(mx, __shfl_xor(mx, 1, 64));
      mx = fmaxf(mx, __shfl_xor(mx, 2, 64));
      mx = fmaxf(mx, __shfl_xor(mx, 4, 64));
      mx = fmaxf(mx, __shfl_xor(mx, 8, 64));
      float nm = fmaxf(m[j], mx);
      al[j] = __expf(m[j] - nm);
      m[j] = nm;
    }
    unsigned pk[4]; float psum[4];
    #pragma unroll
    for (int j=0; j<4; j++){
      float p0 = __expf(mg[0][j] - m[j]);
      float p1 = __expf(mg[1][j] - m[j]);
      bf16_t b0 = (bf16_t)p0, b1 = (bf16_t)p1;
      pk[j] = (unsigned)__builtin_bit_cast(unsigned short, b0)
            | ((unsigned)__builtin_bit_cast(unsigned short, b1) << 16);
      psum[j] = (float)b0 + (float)b1;
    }
    #pragma unroll
    for (int j=0; j<4; j++){
      float s = psum[j];
      s += __shfl_xor(s, 1, 64);
      s += __shfl_xor(s, 2, 64);
      s += __shfl_xor(s, 4, 64);
      s += __shfl_xor(s, 8, 64);
      l[j] = l[j]*al[j] + s;
      #pragma unroll
      for (int df=0; df<4; df++){ accOr[df][j] *= al[j]; accOi[df][j] *= al[j]; }
    }
    // pack P pairs -> b32 LDS stores (lane pair exchange via shfl_xor 1)
    #pragma unroll
    for (int j=0; j<4; j++){
      unsigned partner = (unsigned)__shfl_xor((int)pk[j], 1, 64);
      unsigned word; int kcol;
      if ((fr & 1) == 0){
        word = (pk[j] & 0xFFFFu) | (partner << 16);
        kcol = fr;
      } else {
        word = (partner >> 16) | (pk[j] & 0xFFFF0000u);
        kcol = 15 + fr;
      }
      int q = fq*4 + j;
      *(unsigned*)&Pl[wid][q][kcol] = word;
    }
    __syncthreads();   // P visible; also keeps waves phase-aligned

    // PV: A = P[q=lane&15][k at fq*8], B = V^T[d=lane&15][k at fq*8]
    bf16x8 pa = *(const bf16x8*)&Pl[wid][fr][fq*8];
    #pragma unroll
    for (int df=0; df<4; df++){
      const int dr = df*16 + fr, co = fq*8;
      bf16x8 vrh = *(const bf16x8*)&Vrh[dr][co];
      bf16x8 vrl = *(const bf16x8*)&Vrl[dr][co];
      bf16x8 vih = *(const bf16x8*)&Vih[dr][co];
      bf16x8 vil = *(const bf16x8*)&Vil[dr][co];
      f32x4 cr = accOr[df], ci = accOi[df];
      cr = __builtin_amdgcn_mfma_f32_16x16x32_bf16(pa, vrh, cr, 0,0,0);
      cr = __builtin_amdgcn_mfma_f32_16x16x32_bf16(pa, vrl, cr, 0,0,0);
      ci = __builtin_amdgcn_mfma_f32_16x16x32_bf16(pa, vih, ci, 0,0,0);
      ci = __builtin_amdgcn_mfma_f32_16x16x32_bf16(pa, vil, ci, 0,0,0);
      accOr[df] = cr; accOi[df] = ci;
    }
  }

  // epilogue: out frag col=d=df*16+fr, row=q=fq*4+j
  #pragma unroll
  for (int j=0; j<4; j++){
    float invl = 1.0f / l[j];
    size_t r = (size_t)b*NN + qt*64 + wid*16 + fq*4 + j;
    #pragma unroll
    for (int df=0; df<4; df++){
      int col = h*DD + df*16 + fr;
      aor[r*EE + col] = accOr[df][j] * invl;
      aoi[r*EE + col] = accOi[df][j] * invl;
    }
  }
}

extern "C" void kernel_launch(void* const* d_in, const int* in_sizes, int n_in,
                              void* d_out, int out_size, void* d_ws, size_t ws_size,
                              hipStream_t stream) {
  const float* x       = (const float*)d_in[0];
  const float* g1      = (const float*)d_in[1];
  const float* b1      = (const float*)d_in[2];
  const float* g2      = (const float*)d_in[3];
  const float* b2      = (const float*)d_in[4];
  const float* qkv_wr  = (const float*)d_in[5];
  const float* qkv_wi  = (const float*)d_in[6];
  const float* qkv_br  = (const float*)d_in[7];
  const float* qkv_bi  = (const float*)d_in[8];
  const float* proj_wr = (const float*)d_in[9];
  const float* proj_wi = (const float*)d_in[10];
  const float* proj_br = (const float*)d_in[11];
  const float* proj_bi = (const float*)d_in[12];
  const float* m1_wr   = (const float*)d_in[13];
  const float* m1_wi   = (const float*)d_in[14];
  const float* m1_br   = (const float*)d_in[15];
  const float* m1_bi   = (const float*)d_in[16];
  const float* m2_wr   = (const float*)d_in[17];
  const float* m2_wi   = (const float*)d_in[18];
  const float* m2_br   = (const float*)d_in[19];
  const float* m2_bi   = (const float*)d_in[20];

  float* ws = (float*)d_ws;
  const size_t RE = (size_t)RR * EE;
  // region A (2*RE f32): xn1, then attention output
  float* xn_r  = ws;            float* xn_i  = ws + RE;
  float* ao_r  = ws;            float* ao_i  = ws + RE;
  // region B (6*RE f32 footprint): QKV split bf16 arrays (12*SZH bf16 = same bytes),
  // later reused as xn2 (2*RE) + mlp hidden (4*RE)
  bf16_t* qsplit = (bf16_t*)(ws + 2*RE);
  float* xn2_r = ws + 2*RE;     float* xn2_i = ws + 3*RE;
  float* h_r   = ws + 4*RE;     float* h_i   = ws + 6*RE;
  // region C (2*RE): post-attention residual state x1
  float* x1_r  = ws + 8*RE;     float* x1_i  = ws + 9*RE;

  // 1. LN1 (interleaved in)
  cln_kernel<<<RR, 256, 0, stream>>>(x, nullptr, nullptr, g1, b1, xn_r, xn_i, 0);
  // 2. QKV clinear -> split bf16 arrays for attention
  cgemm_mfma<0,0,2><<<dim3(36,32), 256, 0, stream>>>(
      xn_r, xn_i, qkv_wr, qkv_wi, qkv_br, qkv_bi,
      nullptr, nullptr, nullptr, nullptr, qsplit, EE, 3*EE);
  // 3. attention -> ao [R][E] planar
  cattn_mfma<<<dim3(16,48), 256, 0, stream>>>(qsplit, ao_r, ao_i);
  // 4. proj clinear + residual(original x, interleaved) -> x1 planar
  cgemm_mfma<0,2,0><<<dim3(12,32), 256, 0, stream>>>(
      ao_r, ao_i, proj_wr, proj_wi, proj_br, proj_bi,
      x, nullptr, x1_r, x1_i, nullptr, EE, EE);
  // 5. LN2 (planar in)
  cln_kernel<<<RR, 256, 0, stream>>>(nullptr, x1_r, x1_i, g2, b2, xn2_r, xn2_i, 1);
  // 6. MLP1 + exact gelu -> h [R][1536] planar
  cgemm_mfma<1,0,0><<<dim3(24,32), 256, 0, stream>>>(
      xn2_r, xn2_i, m1_wr, m1_wi, m1_br, m1_bi,
      nullptr, nullptr, h_r, h_i, nullptr, EE, MLPH);
  // 7. MLP2 + residual(x1 planar) -> d_out interleaved
  cgemm_mfma<0,1,1><<<dim3(12,32), 256, 0, stream>>>(
      h_r, h_i, m2_wr, m2_wi, m2_br, m2_bi,
      x1_r, x1_i, (float*)d_out, nullptr, nullptr, MLPH, EE);
}